// Round 6
// baseline (3852.416 us; speedup 1.0000x reference)
//
#include <hip/hip_runtime.h>
#include <stdint.h>

// CoAttention: emb-gather + GRU(75 steps) + co-attention pool + logits.
// Inputs are fp32 in memory (detected at runtime, canonicalized to bf16 in ws).
//
// ws layout (fixed part first, BC-dependent after):
//   flag    int           @ 0          (16 B)
//   smalls  bf16[4720]    @ 16         (9472 B)  bih@0 bhh@1024 wCo@2048
//                                      Wmy@3072 lw@3200 lb@4704 wCob@4712 Wmyb@4713
//   WihImg  bf16          @ 9488       (614400 B)
//   WhhImg  bf16          @ 623888     (614400 B)
//   Wih_c   bf16[270000]  @ 1238288    (540000 B)
//   Whh_c   bf16[270000]  @ 1778288    (540000 B)
//   emb_c   bf16[15e6]    @ 2318288    (30000000 B)
//   gx      fp16          @ 32318288   (15*BC*1920 B)
//   h_all   bf16          @ +gx        (75*BC*640 B)
//   hstate  fp32          @ +h         (BC*1280 B)
// BC=2048 total ~192.2 MB (fits: R4/R5 ran BC=2048 and passed)

typedef float f32x4 __attribute__((ext_vector_type(4)));
typedef short bf16x8 __attribute__((ext_vector_type(8)));
typedef unsigned short u16;
typedef u16 u16x8 __attribute__((ext_vector_type(8)));
typedef u16 u16x4 __attribute__((ext_vector_type(4)));

#define DI __device__ __forceinline__

DI float bf2f(u16 v) {
    uint32_t u = ((uint32_t)v) << 16;
    float f;
    __builtin_memcpy(&f, &u, 4);
    return f;
}
DI u16 f2bf(float f) {  // round-to-nearest-even
    uint32_t u;
    __builtin_memcpy(&u, &f, 4);
    uint32_t r = u + 0x7fffu + ((u >> 16) & 1u);
    return (u16)(r >> 16);
}
DI u16 cvt1(const void* p, int i, int f32m) {
    return f32m ? f2bf(((const float*)p)[i]) : ((const u16*)p)[i];
}

// Load 8 bf16 from a length-300 row, zero-padded to 320. e0 multiple of 8.
DI u16x8 load_row8(const u16* __restrict__ base, int e0) {
    u16x4 z = {0, 0, 0, 0};
    u16x4 lo = (e0 < 300) ? *(const u16x4*)(base + e0) : z;
    u16x4 hi = (e0 + 4 < 300) ? *(const u16x4*)(base + e0 + 4) : z;
    u16x8 r;
    r[0] = lo[0]; r[1] = lo[1]; r[2] = lo[2]; r[3] = lo[3];
    r[4] = hi[0]; r[5] = hi[1]; r[6] = hi[2]; r[7] = hi[3];
    return r;
}

// ---------------------------------------------------------------------------
// Dtype detection (robust to either storage; measured: inputs are fp32).
// ---------------------------------------------------------------------------
__global__ __launch_bounds__(256) void detect_dtype(const u16* __restrict__ raw,
                                                    int* __restrict__ flag) {
    __shared__ int cnt;
    if (threadIdx.x == 0) cnt = 0;
    __syncthreads();
    int local = 0;
    for (int i = threadIdx.x; i < 4096; i += 256) {
        int e = (raw[i] >> 7) & 0xFF;
        if (e >= 140) local++;
    }
    atomicAdd(&cnt, local);
    __syncthreads();
    if (threadIdx.x == 0) flag[0] = (cnt > 256) ? 1 : 0;
}

__global__ __launch_bounds__(256) void conv_big(const void* __restrict__ in,
                                                u16* __restrict__ outp, int n,
                                                const int* __restrict__ flag) {
    const int f32m = flag[0];
    int i0 = (blockIdx.x * 256 + threadIdx.x) * 8;
#pragma unroll
    for (int k = 0; k < 8; k++) {
        int i = i0 + k;
        if (i < n) outp[i] = cvt1(in, i, f32m);
    }
}

__global__ __launch_bounds__(256) void conv_smalls(
    const void* bih_r, const void* bhh_r, const void* wCo_r, const void* wCob_r,
    const void* Wmy_r, const void* Wmyb_r, const void* lw_r, const void* lb_r,
    u16* __restrict__ smalls, const int* __restrict__ flag) {
    const int f32m = flag[0];
    int t = blockIdx.x * 256 + threadIdx.x;
    if (t < 900) smalls[t] = cvt1(bih_r, t, f32m);
    else if (t < 1800) smalls[1024 + t - 900] = cvt1(bhh_r, t - 900, f32m);
    else if (t < 2700) smalls[2048 + t - 1800] = cvt1(wCo_r, t - 1800, f32m);
    else if (t < 2775) smalls[3072 + t - 2700] = cvt1(Wmy_r, t - 2700, f32m);
    else if (t < 4275) smalls[3200 + t - 2775] = cvt1(lw_r, t - 2775, f32m);
    else if (t < 4280) smalls[4704 + t - 4275] = cvt1(lb_r, t - 4275, f32m);
    else if (t == 4280) smalls[4712] = cvt1(wCob_r, 0, f32m);
    else if (t == 4281) smalls[4713] = cvt1(Wmyb_r, 0, f32m);
}

// ---------------------------------------------------------------------------
// Pack a (900 x 300) canonical bf16 weight into MFMA B-fragment image:
// img[nt<60][kt<10][lane<64][8], g = nt*16 + (lane&15) in padded 960 space
// (g = gate*320 + u), k = kt*32 + (lane>>4)*8 + j. Zero pad u>=300, e>=300.
// ---------------------------------------------------------------------------
__global__ __launch_bounds__(256) void prep_img(const u16* __restrict__ W,
                                                u16* __restrict__ img) {
    int t = blockIdx.x * 256 + threadIdx.x;  // 38400 threads
    if (t >= 60 * 10 * 64) return;
    int lane = t & 63;
    int kt = (t >> 6) % 10;
    int nt = t / 640;
    int g = nt * 16 + (lane & 15);
    int gate = g / 320, u = g - gate * 320;
    int e0 = kt * 32 + (lane >> 4) * 8;
    u16x8 v;
    if (u < 300) {
        v = load_row8(W + (size_t)(gate * 300 + u) * 300, e0);
    } else {
        u16x8 z = {0, 0, 0, 0, 0, 0, 0, 0};
        v = z;
    }
    *(u16x8*)&img[(size_t)t * 8] = v;
}

__global__ __launch_bounds__(256) void zero_hstate(float* __restrict__ hs) {
    int t = blockIdx.x * 256 + threadIdx.x;
    f32x4 z = {0.f, 0.f, 0.f, 0.f};
    ((f32x4*)hs)[t] = z;
}

// ---------------------------------------------------------------------------
// GEMM1 (one time-chunk of one phase):
// gx[m][g] = sum_e emb[ids(m)][e]*W_ih[g][e] + b_ih[g], m = t'*BC + bc.
// Tile 192(M) x 192(N), K=320 (10 k-tiles). Grid (15*BC/192, 5).
// ---------------------------------------------------------------------------
__global__ __launch_bounds__(256, 2) void gemm1_kernel(
    const int* __restrict__ seq, const u16* __restrict__ emb,
    const u16* __restrict__ Wimg, const u16* __restrict__ bih,
    _Float16* __restrict__ gx, int ck, int phase, int BC, int bshift) {
    __shared__ int ids[192];
    __shared__ __align__(16) u16 Aimg[12 * 64 * 8];
    __shared__ __align__(16) u16 Bbuf[12 * 64 * 8];

    const int tid = threadIdx.x;
    const int lane = tid & 63, wv = tid >> 6, q = lane >> 4, c = lane & 15;
    const int m0 = blockIdx.x * 192;
    const int nb = blockIdx.y;

    if (tid < 192) {
        int m = m0 + tid;
        int bc = m & (BC - 1);
        int tp = m >> bshift;
        ids[tid] = seq[(size_t)(phase * BC + bc) * 75 + ck * 15 + tp];
    }
    __syncthreads();

    f32x4 acc[3][12];
#pragma unroll
    for (int mt = 0; mt < 3; mt++)
#pragma unroll
        for (int nt = 0; nt < 12; nt++) {
            f32x4 z = {0.f, 0.f, 0.f, 0.f};
            acc[mt][nt] = z;
        }

    for (int kt = 0; kt < 10; kt++) {
#pragma unroll
        for (int s = 0; s < 3; s++) {
            int o = tid + s * 256;
            int qq = o / 192;
            int r = o - qq * 192;
            int e0 = kt * 32 + qq * 8;
            u16x8 v = load_row8(emb + (size_t)ids[r] * 300, e0);
            *(u16x8*)&Aimg[(((r >> 4) * 64) + ((r & 15) | (qq << 4))) * 8] = v;
        }
#pragma unroll
        for (int s = 0; s < 3; s++) {
            int ch = tid + s * 256;
            *(u16x8*)&Bbuf[ch * 8] =
                *(const u16x8*)&Wimg[(((size_t)(nb * 12 + (ch >> 6)) * 10 + kt) * 64 + (ch & 63)) * 8];
        }
        __syncthreads();

        bf16x8 a[3];
#pragma unroll
        for (int mt = 0; mt < 3; mt++) {
            u16x8 tmp = *(const u16x8*)&Aimg[(((wv * 3 + mt) * 64) + lane) * 8];
            a[mt] = __builtin_bit_cast(bf16x8, tmp);
        }
#pragma unroll
        for (int nt = 0; nt < 12; nt++) {
            u16x8 tb = *(const u16x8*)&Bbuf[(nt * 64 + lane) * 8];
            bf16x8 b = __builtin_bit_cast(bf16x8, tb);
#pragma unroll
            for (int mt = 0; mt < 3; mt++)
                acc[mt][nt] = __builtin_amdgcn_mfma_f32_16x16x32_bf16(a[mt], b, acc[mt][nt], 0, 0, 0);
        }
        __syncthreads();
    }

#pragma unroll
    for (int nt = 0; nt < 12; nt++) {
        int g = nb * 192 + nt * 16 + c;
        int gate = g / 320, u = g - gate * 320;
        float bias = (u < 300) ? bf2f(bih[gate * 300 + u]) : 0.f;
#pragma unroll
        for (int mt = 0; mt < 3; mt++) {
            int mrow = m0 + (wv * 3 + mt) * 16 + q * 4;
#pragma unroll
            for (int reg = 0; reg < 4; reg++) {
                gx[(size_t)(mrow + reg) * 960 + g] = (_Float16)(acc[mt][nt][reg] + bias);
            }
        }
    }
}

// ---------------------------------------------------------------------------
// GRU chunk: BC/32 WGs x 512 threads (8 waves). WG owns 32 batch rows and
// scans 15 steps. h in LDS as bf16 hi+lo fragment images; fp32 h in regs.
// Wave w owns unit tiles T = w + 8*Ti (Ti<3, T<20: waves 0-3 have 3 tiles,
// 4-7 have 2) and BOTH batch tiles mt=0,1 -> no duplicate W-fragment reads,
// complete (r,z,n) gate triples stay in-lane. __launch_bounds__(512,2)
// pins the allocator at 2 waves/EU (cap 256 VGPR) -> no scratch spill
// (R5 lesson: 640thr/(640,1) squeezed to 84 VGPR and spilled ~250MB/disp).
// gx is nontemporal-loaded and h_all nontemporal-stored so the streamed
// gx cannot evict the L2-resident W_hh image.
// ---------------------------------------------------------------------------
__global__ __launch_bounds__(512, 2) void gru_chunk(
    const _Float16* __restrict__ gx, const u16* __restrict__ Wimg,
    const u16* __restrict__ bhh_g, u16* __restrict__ h_all,
    float* __restrict__ hstate, int ck, int BC) {
    __shared__ __align__(16) u16 Hhi[2 * 10 * 64 * 8];  // 20 KB [mt][kt][lane][8]
    __shared__ __align__(16) u16 Hlo[2 * 10 * 64 * 8];  // 20 KB

    const int tid = threadIdx.x;
    const int lane = tid & 63, wv = tid >> 6, q = lane >> 4, c = lane & 15;
    const int b0 = blockIdx.x * 32;
    const int nTi = (wv < 4) ? 3 : 2;  // T = wv + 8*Ti, T < 20

    float bhh[3][3];
#pragma unroll
    for (int Ti = 0; Ti < 3; Ti++) {
        int u = (wv + 8 * Ti) * 16 + c;
#pragma unroll
        for (int g = 0; g < 3; g++)
            bhh[Ti][g] = (Ti < nTi && u < 300) ? bf2f(bhh_g[g * 300 + u]) : 0.f;
    }

    // Load carried h state (fp32) and build hi/lo fragment images.
    float hm[2][3][4];
#pragma unroll
    for (int mt = 0; mt < 2; mt++)
#pragma unroll
        for (int Ti = 0; Ti < 3; Ti++) {
            if (Ti >= nTi) continue;
            int T = wv + 8 * Ti;
            int u = T * 16 + c;
            int kt = T >> 1;
            int qp = ((T & 1) << 1) | (c >> 3);
            int j = c & 7;
#pragma unroll
            for (int reg = 0; reg < 4; reg++) {
                int m = mt * 16 + q * 4 + reg;
                float h = hstate[(size_t)(b0 + m) * 320 + u];
                hm[mt][Ti][reg] = h;
                int idx = ((mt * 10 + kt) * 64 + ((q * 4 + reg) | (qp << 4))) * 8 + j;
                u16 hi = f2bf(h);
                Hhi[idx] = hi;
                Hlo[idx] = f2bf(h - bf2f(hi));
            }
        }
    __syncthreads();

    for (int tt = 0; tt < 15; tt++) {
        f32x4 acc[2][3][3];
#pragma unroll
        for (int mt = 0; mt < 2; mt++)
#pragma unroll
            for (int Ti = 0; Ti < 3; Ti++)
#pragma unroll
                for (int g = 0; g < 3; g++) {
                    f32x4 z = {0.f, 0.f, 0.f, 0.f};
                    acc[mt][Ti][g] = z;
                }

        // gh = (h_hi + h_lo) @ W_hh^T  (K = 320, 10 k-tiles)
        for (int kt = 0; kt < 10; kt++) {
            bf16x8 ahi[2], alo[2];
#pragma unroll
            for (int mt = 0; mt < 2; mt++) {
                u16x8 th = *(const u16x8*)&Hhi[((mt * 10 + kt) * 64 + lane) * 8];
                u16x8 tl = *(const u16x8*)&Hlo[((mt * 10 + kt) * 64 + lane) * 8];
                ahi[mt] = __builtin_bit_cast(bf16x8, th);
                alo[mt] = __builtin_bit_cast(bf16x8, tl);
            }
            bf16x8 bf[3][3];
#pragma unroll
            for (int Ti = 0; Ti < 3; Ti++) {
                if (Ti >= nTi) continue;
#pragma unroll
                for (int g = 0; g < 3; g++) {
                    int nt = g * 20 + wv + 8 * Ti;
                    u16x8 tb = *(const u16x8*)&Wimg[((size_t)(nt * 10 + kt) * 64 + lane) * 8];
                    bf[Ti][g] = __builtin_bit_cast(bf16x8, tb);
                }
            }
#pragma unroll
            for (int Ti = 0; Ti < 3; Ti++) {
                if (Ti >= nTi) continue;
#pragma unroll
                for (int g = 0; g < 3; g++)
#pragma unroll
                    for (int mt = 0; mt < 2; mt++) {
                        acc[mt][Ti][g] = __builtin_amdgcn_mfma_f32_16x16x32_bf16(
                            ahi[mt], bf[Ti][g], acc[mt][Ti][g], 0, 0, 0);
                        acc[mt][Ti][g] = __builtin_amdgcn_mfma_f32_16x16x32_bf16(
                            alo[mt], bf[Ti][g], acc[mt][Ti][g], 0, 0, 0);
                    }
            }
        }

        // Gates (C layout: col=lane&15 -> u, row=q*4+reg -> m)
        const _Float16* gxt = gx + ((size_t)tt * BC + b0) * 960;
        const int tglob = ck * 15 + tt;
#pragma unroll
        for (int mt = 0; mt < 2; mt++)
#pragma unroll
            for (int Ti = 0; Ti < 3; Ti++) {
                if (Ti >= nTi) continue;
                int u = (wv + 8 * Ti) * 16 + c;
#pragma unroll
                for (int reg = 0; reg < 4; reg++) {
                    int m = mt * 16 + q * 4 + reg;
                    size_t ro = (size_t)m * 960;
                    float xr = (float)__builtin_nontemporal_load(&gxt[ro + u]);
                    float xz = (float)__builtin_nontemporal_load(&gxt[ro + 320 + u]);
                    float xn = (float)__builtin_nontemporal_load(&gxt[ro + 640 + u]);
                    float hr = acc[mt][Ti][0][reg] + bhh[Ti][0];
                    float hz = acc[mt][Ti][1][reg] + bhh[Ti][1];
                    float hn = acc[mt][Ti][2][reg] + bhh[Ti][2];
                    float r = 1.f / (1.f + __expf(-(xr + hr)));
                    float z = 1.f / (1.f + __expf(-(xz + hz)));
                    float ex = __expf(2.f * (xn + r * hn));
                    float n = 1.f - 2.f / (ex + 1.f);  // tanh
                    float h = (1.f - z) * n + z * hm[mt][Ti][reg];
                    hm[mt][Ti][reg] = h;
                    __builtin_nontemporal_store(
                        f2bf(h), &h_all[((size_t)tglob * BC + (b0 + m)) * 320 + u]);
                }
            }
        __syncthreads();  // fragment reads of h(t-1) done

        // Write new h into fragment images (hi + lo)
#pragma unroll
        for (int mt = 0; mt < 2; mt++)
#pragma unroll
            for (int Ti = 0; Ti < 3; Ti++) {
                if (Ti >= nTi) continue;
                int T = wv + 8 * Ti;
                int kt = T >> 1;
                int qp = ((T & 1) << 1) | (c >> 3);
                int j = c & 7;
#pragma unroll
                for (int reg = 0; reg < 4; reg++) {
                    int idx = ((mt * 10 + kt) * 64 + ((q * 4 + reg) | (qp << 4))) * 8 + j;
                    float h = hm[mt][Ti][reg];
                    u16 hi = f2bf(h);
                    Hhi[idx] = hi;
                    Hlo[idx] = f2bf(h - bf2f(hi));
                }
            }
        __syncthreads();
    }

    // Persist fp32 h state for the next chunk.
#pragma unroll
    for (int mt = 0; mt < 2; mt++)
#pragma unroll
        for (int Ti = 0; Ti < 3; Ti++) {
            if (Ti >= nTi) continue;
            int u = (wv + 8 * Ti) * 16 + c;
#pragma unroll
            for (int reg = 0; reg < 4; reg++) {
                int m = mt * 16 + q * 4 + reg;
                hstate[(size_t)(b0 + m) * 320 + u] = hm[mt][Ti][reg];
            }
        }
}

// ---------------------------------------------------------------------------
// Co-attention + pool + logits. One WG per batch row of the phase.
// ---------------------------------------------------------------------------
__global__ __launch_bounds__(256, 2) void coattn_kernel(
    const u16* __restrict__ h_all, const u16* __restrict__ smalls,
    void* __restrict__ outv, const int* __restrict__ flag, int phase, int BC) {
    __shared__ __align__(16) u16 himg[5 * 10 * 64 * 8];
    __shared__ float smacc[80], aArr[80], bArr[80], diagArr[80], attn[80], smv[80];
    __shared__ float pooled[320];
    __shared__ float scal[2];

    const u16* wCo = smalls + 2048;
    const u16* Wmy = smalls + 3072;
    const u16* lw = smalls + 3200;
    const u16* lb = smalls + 4704;
    const int f32out = flag[0];

    const int b = blockIdx.x;
    const int tid = threadIdx.x;
    const int lane = tid & 63, wv = tid >> 6, q = lane >> 4, c = lane & 15;

    for (int o = tid; o < 3200; o += 256) {
        int i = o / 40;
        int oc = o - i * 40;
        int kt = oc >> 2, qq = oc & 3;
        int e0 = kt * 32 + qq * 8;
        u16x8 v = {0, 0, 0, 0, 0, 0, 0, 0};
        if (i < 75) v = *(const u16x8*)(h_all + ((size_t)i * BC + b) * 320 + e0);
        *(u16x8*)&himg[(((i >> 4) * 10 + kt) * 64 + ((i & 15) | (qq << 4))) * 8] = v;
    }
    if (tid < 80) {
        smacc[tid] = 0.f; aArr[tid] = 0.f; bArr[tid] = 0.f;
        diagArr[tid] = 0.f; attn[tid] = 0.f;
    }
    __syncthreads();

    for (int pass = 0; pass < 2; pass++) {
        if (pass == 1 && wv != 0) break;
        int nt = (pass == 0) ? wv : 4;
        int jj = nt * 16 + c;
        bf16x8 bfr[10];
#pragma unroll
        for (int kt = 0; kt < 10; kt++) {
            int e0 = kt * 32 + q * 8;
            u16x8 res = {0, 0, 0, 0, 0, 0, 0, 0};
            if (jj < 75) {
                u16x8 hv = *(const u16x8*)&himg[((nt * 10 + kt) * 64 + lane) * 8];
                u16x8 wcv = load_row8(wCo + 600, e0);
#pragma unroll
                for (int j = 0; j < 8; j++) res[j] = f2bf(bf2f(hv[j]) * bf2f(wcv[j]));
            } else if (jj == 75) {
                res = load_row8(wCo, e0);  // wa
            } else if (jj == 76) {
                res = load_row8(wCo + 300, e0);  // wb
            }
            bfr[kt] = __builtin_bit_cast(bf16x8, res);
        }
        float wmyj = (jj < 75) ? bf2f(Wmy[jj]) : 0.f;

        for (int mt = 0; mt < 5; mt++) {
            f32x4 acc = {0.f, 0.f, 0.f, 0.f};
#pragma unroll
            for (int kt = 0; kt < 10; kt++) {
                u16x8 ta = *(const u16x8*)&himg[((mt * 10 + kt) * 64 + lane) * 8];
                bf16x8 a = __builtin_bit_cast(bf16x8, ta);
                acc = __builtin_amdgcn_mfma_f32_16x16x32_bf16(a, bfr[kt], acc, 0, 0, 0);
            }
#pragma unroll
            for (int reg = 0; reg < 4; reg++) {
                int i = mt * 16 + q * 4 + reg;
                float v = acc[reg];
                float p = v * wmyj;
                p += __shfl_xor(p, 1);
                p += __shfl_xor(p, 2);
                p += __shfl_xor(p, 4);
                p += __shfl_xor(p, 8);
                if (c == 0 && i < 75) atomicAdd(&smacc[i], p);
                if (jj == i && i < 75) diagArr[i] = v;
                if (jj == 75) aArr[i] = v;
                if (jj == 76) bArr[i] = v;
            }
        }
    }
    __syncthreads();

    if (tid < 64) {
        float w1 = bf2f(Wmy[tid]);
        float w2 = (tid + 64 < 75) ? bf2f(Wmy[tid + 64]) : 0.f;
        float s1 = w1 + w2;
        float s2 = w1 * bArr[tid] + ((tid + 64 < 75) ? w2 * bArr[tid + 64] : 0.f);
#pragma unroll
        for (int m = 1; m < 64; m <<= 1) {
            s1 += __shfl_xor(s1, m);
            s2 += __shfl_xor(s2, m);
        }
        if (tid == 0) { scal[0] = s1; scal[1] = s2; }
    }
    __syncthreads();

    float cb = bf2f(smalls[4712]);
    float wmyb = bf2f(smalls[4713]);
    if (tid < 75) {
        float Wi = bf2f(Wmy[tid]);
        smv[tid] = smacc[tid] - diagArr[tid] * Wi + (aArr[tid] + cb) * (scal[0] - Wi) +
                   scal[1] - bArr[tid] * Wi + wmyb;
    }
    __syncthreads();

    if (tid < 64) {
        float v1 = smv[tid];
        float v2 = (tid + 64 < 75) ? smv[tid + 64] : -1e30f;
        float mx = fmaxf(v1, v2);
#pragma unroll
        for (int m = 1; m < 64; m <<= 1) mx = fmaxf(mx, __shfl_xor(mx, m));
        float e1 = __expf(v1 - mx);
        float e2 = (tid + 64 < 75) ? __expf(v2 - mx) : 0.f;
        float s = e1 + e2;
#pragma unroll
        for (int m = 1; m < 64; m <<= 1) s += __shfl_xor(s, m);
        attn[tid] = e1 / s;
        if (tid + 64 < 75) attn[tid + 64] = e2 / s;
    }
    __syncthreads();

    for (int d = tid; d < 320; d += 256) {
        float accp = 0.f;
        for (int i = 0; i < 75; i++)
            accp += attn[i] * bf2f(h_all[((size_t)i * BC + b) * 320 + d]);
        pooled[d] = accp;
    }
    __syncthreads();

    if (tid < 160) {
        int o = tid >> 5, d0 = tid & 31;
        float accl = 0.f;
        for (int d = d0; d < 320; d += 32)
            accl += (d < 300) ? pooled[d] * bf2f(lw[o * 300 + d]) : 0.f;
#pragma unroll
        for (int m = 1; m < 32; m <<= 1) accl += __shfl_xor(accl, m);
        if (d0 == 0) {
            float v = accl + bf2f(lb[o]);
            size_t idx = (size_t)(phase * BC + b) * 5 + o;
            if (f32out) ((float*)outv)[idx] = v;
            else ((u16*)outv)[idx] = f2bf(v);
        }
    }
}

// ---------------------------------------------------------------------------
extern "C" void kernel_launch(void* const* d_in, const int* in_sizes, int n_in,
                              void* d_out, int out_size, void* d_ws, size_t ws_size,
                              hipStream_t stream) {
    const int* seq = (const int*)d_in[0];

    // Fixed-offset canonical region
    char* p = (char*)d_ws;
    int* flag = (int*)p;                        // @0
    u16* smalls = (u16*)(p + 16);               // 4720 u16
    u16* WihImg = (u16*)(p + 9488);
    u16* WhhImg = (u16*)(p + 623888);
    u16* Wih_c = (u16*)(p + 1238288);
    u16* Whh_c = (u16*)(p + 1778288);
    u16* emb_c = (u16*)(p + 2318288);
    const unsigned long long fixed_end = 32318288ull;

    auto req = [&](long long BC) -> unsigned long long {
        return fixed_end + (unsigned long long)BC * 78080ull + 1048576ull;  // +1MB slack
    };
    int BC = 256, bshift = 8;
    if (ws_size >= req(2048)) { BC = 2048; bshift = 11; }
    else if (ws_size >= req(1024)) { BC = 1024; bshift = 10; }
    else if (ws_size >= req(512)) { BC = 512; bshift = 9; }
    const int P = 2048 / BC;

    unsigned long long gx_b = 15ull * BC * 1920ull;
    unsigned long long h_b = 75ull * BC * 640ull;
    _Float16* gx = (_Float16*)(p + fixed_end);
    u16* h_all = (u16*)(p + fixed_end + gx_b);
    float* hstate = (float*)(p + fixed_end + gx_b + h_b);

    // 1. dtype detection + canonicalization
    detect_dtype<<<dim3(1), dim3(256), 0, stream>>>((const u16*)d_in[1], flag);
    conv_big<<<dim3((15000000 + 2047) / 2048), dim3(256), 0, stream>>>(
        d_in[1], emb_c, 15000000, flag);
    conv_big<<<dim3((270000 + 2047) / 2048), dim3(256), 0, stream>>>(
        d_in[2], Wih_c, 270000, flag);
    conv_big<<<dim3((270000 + 2047) / 2048), dim3(256), 0, stream>>>(
        d_in[3], Whh_c, 270000, flag);
    conv_smalls<<<dim3(17), dim3(256), 0, stream>>>(
        d_in[4], d_in[5], d_in[6], d_in[7], d_in[8], d_in[9], d_in[10], d_in[11],
        smalls, flag);

    // 2. weight fragment images
    prep_img<<<dim3(150), dim3(256), 0, stream>>>(Wih_c, WihImg);
    prep_img<<<dim3(150), dim3(256), 0, stream>>>(Whh_c, WhhImg);

    // 3. phases
    for (int phase = 0; phase < P; phase++) {
        zero_hstate<<<dim3(BC * 320 / 1024), dim3(256), 0, stream>>>(hstate);
        for (int ck = 0; ck < 5; ck++) {
            gemm1_kernel<<<dim3(15 * BC / 192, 5), dim3(256), 0, stream>>>(
                seq, emb_c, WihImg, smalls /*bih*/, gx, ck, phase, BC, bshift);
            gru_chunk<<<dim3(BC / 32), dim3(512), 0, stream>>>(
                gx, WhhImg, smalls + 1024 /*bhh*/, h_all, hstate, ck, BC);
        }
        coattn_kernel<<<dim3(BC), dim3(256), 0, stream>>>(h_all, smalls, d_out, flag,
                                                          phase, BC);
    }
}

// Round 7
// 3041.920 us; speedup vs baseline: 1.2664x; 1.2664x over previous
//
#include <hip/hip_runtime.h>
#include <stdint.h>

// CoAttention: emb-gather + GRU(75 steps) + co-attention pool + logits.
// Inputs are fp32 in memory (detected at runtime; weights canonicalized to
// bf16 in ws; emb converted on the fly in gemm1).
//
// ws layout:
//   flag    int           @ 0          (16 B)
//   smalls  bf16[4720]    @ 16         (9472 B)
//   WihImg  bf16          @ 9488       (614400 B)
//   WhhImg  bf16          @ 623888     (614400 B)
//   Wih_c   bf16[270000]  @ 1238288    (540000 B)
//   Whh_c   bf16[270000]  @ 1778288    (540000 B)
//   gxn     fp16          @ 2318288    (15*BC*2560 B)  gate-packed (r,z,n,pad)
//   h_all   bf16          @ +gxn       (75*BC*640 B)
//   hstate  fp32          @ +h         (BC*1280 B)
// BC=2048 total ~182.9 MB (< R4's proven 193.3 MB budget)

typedef float f32x4 __attribute__((ext_vector_type(4)));
typedef short bf16x8 __attribute__((ext_vector_type(8)));
typedef _Float16 f16x4 __attribute__((ext_vector_type(4)));
typedef unsigned short u16;
typedef u16 u16x8 __attribute__((ext_vector_type(8)));
typedef u16 u16x4 __attribute__((ext_vector_type(4)));

#define DI __device__ __forceinline__

DI float bf2f(u16 v) {
    uint32_t u = ((uint32_t)v) << 16;
    float f;
    __builtin_memcpy(&f, &u, 4);
    return f;
}
DI u16 f2bf(float f) {  // round-to-nearest-even
    uint32_t u;
    __builtin_memcpy(&u, &f, 4);
    uint32_t r = u + 0x7fffu + ((u >> 16) & 1u);
    return (u16)(r >> 16);
}
DI u16 cvt1(const void* p, int i, int f32m) {
    return f32m ? f2bf(((const float*)p)[i]) : ((const u16*)p)[i];
}

// Load 8 bf16 from a length-300 bf16 row, zero-padded to 320. e0 mult of 8.
DI u16x8 load_row8(const u16* __restrict__ base, int e0) {
    u16x4 z = {0, 0, 0, 0};
    u16x4 lo = (e0 < 300) ? *(const u16x4*)(base + e0) : z;
    u16x4 hi = (e0 + 4 < 300) ? *(const u16x4*)(base + e0 + 4) : z;
    u16x8 r;
    r[0] = lo[0]; r[1] = lo[1]; r[2] = lo[2]; r[3] = lo[3];
    r[4] = hi[0]; r[5] = hi[1]; r[6] = hi[2]; r[7] = hi[3];
    return r;
}
// Same from an fp32 row (on-the-fly bf16 conversion).
DI u16x8 load_row8_f32(const float* __restrict__ base, int e0) {
    f32x4 z = {0.f, 0.f, 0.f, 0.f};
    f32x4 lo = (e0 < 300) ? *(const f32x4*)(base + e0) : z;
    f32x4 hi = (e0 + 4 < 300) ? *(const f32x4*)(base + e0 + 4) : z;
    u16x8 r;
    r[0] = f2bf(lo[0]); r[1] = f2bf(lo[1]); r[2] = f2bf(lo[2]); r[3] = f2bf(lo[3]);
    r[4] = f2bf(hi[0]); r[5] = f2bf(hi[1]); r[6] = f2bf(hi[2]); r[7] = f2bf(hi[3]);
    return r;
}

// ---------------------------------------------------------------------------
__global__ __launch_bounds__(256) void detect_dtype(const u16* __restrict__ raw,
                                                    int* __restrict__ flag) {
    __shared__ int cnt;
    if (threadIdx.x == 0) cnt = 0;
    __syncthreads();
    int local = 0;
    for (int i = threadIdx.x; i < 4096; i += 256) {
        int e = (raw[i] >> 7) & 0xFF;
        if (e >= 140) local++;
    }
    atomicAdd(&cnt, local);
    __syncthreads();
    if (threadIdx.x == 0) flag[0] = (cnt > 256) ? 1 : 0;
}

__global__ __launch_bounds__(256) void conv_big(const void* __restrict__ in,
                                                u16* __restrict__ outp, int n,
                                                const int* __restrict__ flag) {
    const int f32m = flag[0];
    int i0 = (blockIdx.x * 256 + threadIdx.x) * 8;
#pragma unroll
    for (int k = 0; k < 8; k++) {
        int i = i0 + k;
        if (i < n) outp[i] = cvt1(in, i, f32m);
    }
}

__global__ __launch_bounds__(256) void conv_smalls(
    const void* bih_r, const void* bhh_r, const void* wCo_r, const void* wCob_r,
    const void* Wmy_r, const void* Wmyb_r, const void* lw_r, const void* lb_r,
    u16* __restrict__ smalls, const int* __restrict__ flag) {
    const int f32m = flag[0];
    int t = blockIdx.x * 256 + threadIdx.x;
    if (t < 900) smalls[t] = cvt1(bih_r, t, f32m);
    else if (t < 1800) smalls[1024 + t - 900] = cvt1(bhh_r, t - 900, f32m);
    else if (t < 2700) smalls[2048 + t - 1800] = cvt1(wCo_r, t - 1800, f32m);
    else if (t < 2775) smalls[3072 + t - 2700] = cvt1(Wmy_r, t - 2700, f32m);
    else if (t < 4275) smalls[3200 + t - 2775] = cvt1(lw_r, t - 2775, f32m);
    else if (t < 4280) smalls[4704 + t - 4275] = cvt1(lb_r, t - 4275, f32m);
    else if (t == 4280) smalls[4712] = cvt1(wCob_r, 0, f32m);
    else if (t == 4281) smalls[4713] = cvt1(Wmyb_r, 0, f32m);
}

// ---------------------------------------------------------------------------
// Pack a (900 x 300) canonical bf16 weight into MFMA B-fragment image:
// img[nt<60][kt<10][lane<64][8], g = nt*16 + (lane&15) in padded 960 space.
// ---------------------------------------------------------------------------
__global__ __launch_bounds__(256) void prep_img(const u16* __restrict__ W,
                                                u16* __restrict__ img) {
    int t = blockIdx.x * 256 + threadIdx.x;
    if (t >= 60 * 10 * 64) return;
    int lane = t & 63;
    int kt = (t >> 6) % 10;
    int nt = t / 640;
    int g = nt * 16 + (lane & 15);
    int gate = g / 320, u = g - gate * 320;
    int e0 = kt * 32 + (lane >> 4) * 8;
    u16x8 v;
    if (u < 300) {
        v = load_row8(W + (size_t)(gate * 300 + u) * 300, e0);
    } else {
        u16x8 z = {0, 0, 0, 0, 0, 0, 0, 0};
        v = z;
    }
    *(u16x8*)&img[(size_t)t * 8] = v;
}

__global__ __launch_bounds__(256) void zero_hstate(float* __restrict__ hs) {
    int t = blockIdx.x * 256 + threadIdx.x;
    f32x4 z = {0.f, 0.f, 0.f, 0.f};
    ((f32x4*)hs)[t] = z;
}

// ---------------------------------------------------------------------------
// GEMM1: gxn[(m*320+u)*4+gate] = sum_e emb[ids(m)][e]*W_ih[g][e] + b_ih[g],
// fp16, gate-packed per (m,u) so the GRU loads one dwordx2 per element.
// Tile 192x192, K=320. Grid (15*BC/192, 5). emb read raw (fp32 or bf16).
// ---------------------------------------------------------------------------
__global__ __launch_bounds__(256, 2) void gemm1_kernel(
    const int* __restrict__ seq, const void* __restrict__ emb_raw,
    const u16* __restrict__ Wimg, const u16* __restrict__ bih,
    _Float16* __restrict__ gxn, int ck, int phase, int BC, int bshift,
    const int* __restrict__ flag) {
    __shared__ int ids[192];
    __shared__ __align__(16) u16 Aimg[12 * 64 * 8];
    __shared__ __align__(16) u16 Bbuf[12 * 64 * 8];

    const int tid = threadIdx.x;
    const int lane = tid & 63, wv = tid >> 6, q = lane >> 4, c = lane & 15;
    const int m0 = blockIdx.x * 192;
    const int nb = blockIdx.y;
    const int f32m = flag[0];

    if (tid < 192) {
        int m = m0 + tid;
        int bc = m & (BC - 1);
        int tp = m >> bshift;
        ids[tid] = seq[(size_t)(phase * BC + bc) * 75 + ck * 15 + tp];
    }
    __syncthreads();

    f32x4 acc[3][12];
#pragma unroll
    for (int mt = 0; mt < 3; mt++)
#pragma unroll
        for (int nt = 0; nt < 12; nt++) {
            f32x4 z = {0.f, 0.f, 0.f, 0.f};
            acc[mt][nt] = z;
        }

    for (int kt = 0; kt < 10; kt++) {
#pragma unroll
        for (int s = 0; s < 3; s++) {
            int o = tid + s * 256;
            int qq = o / 192;
            int r = o - qq * 192;
            int e0 = kt * 32 + qq * 8;
            u16x8 v = f32m ? load_row8_f32((const float*)emb_raw + (size_t)ids[r] * 300, e0)
                           : load_row8((const u16*)emb_raw + (size_t)ids[r] * 300, e0);
            *(u16x8*)&Aimg[(((r >> 4) * 64) + ((r & 15) | (qq << 4))) * 8] = v;
        }
#pragma unroll
        for (int s = 0; s < 3; s++) {
            int ch = tid + s * 256;
            *(u16x8*)&Bbuf[ch * 8] =
                *(const u16x8*)&Wimg[(((size_t)(nb * 12 + (ch >> 6)) * 10 + kt) * 64 + (ch & 63)) * 8];
        }
        __syncthreads();

        bf16x8 a[3];
#pragma unroll
        for (int mt = 0; mt < 3; mt++) {
            u16x8 tmp = *(const u16x8*)&Aimg[(((wv * 3 + mt) * 64) + lane) * 8];
            a[mt] = __builtin_bit_cast(bf16x8, tmp);
        }
#pragma unroll
        for (int nt = 0; nt < 12; nt++) {
            u16x8 tb = *(const u16x8*)&Bbuf[(nt * 64 + lane) * 8];
            bf16x8 b = __builtin_bit_cast(bf16x8, tb);
#pragma unroll
            for (int mt = 0; mt < 3; mt++)
                acc[mt][nt] = __builtin_amdgcn_mfma_f32_16x16x32_bf16(a[mt], b, acc[mt][nt], 0, 0, 0);
        }
        __syncthreads();
    }

    // Epilogue: + b_ih, store fp16 gate-packed: gxn[(m*320+u)*4 + gate].
#pragma unroll
    for (int nt = 0; nt < 12; nt++) {
        int g = nb * 192 + nt * 16 + c;
        int gate = g / 320, u = g - gate * 320;
        float bias = (u < 300) ? bf2f(bih[gate * 300 + u]) : 0.f;
#pragma unroll
        for (int mt = 0; mt < 3; mt++) {
            int mrow = m0 + (wv * 3 + mt) * 16 + q * 4;
#pragma unroll
            for (int reg = 0; reg < 4; reg++) {
                gxn[((size_t)(mrow + reg) * 320 + u) * 4 + gate] =
                    (_Float16)(acc[mt][nt][reg] + bias);
            }
        }
    }
}

// ---------------------------------------------------------------------------
// GRU chunk: BC/32 WGs x 256 threads (4 waves, R4's proven no-spill config,
// __launch_bounds__(256,1): register cap 512/wave, occupancy already
// 1 wave/SIMD so extra registers are free). Latency attacked with ILP:
//  - all 40 gate-input dwordx2 loads issued at step start (hidden under W)
//  - W fragments ping-pong double-buffered across kt (kt+1 loads in flight
//    during kt's MFMAs; kt unrolled by 2 so no register copies)
// W fragments are wave-private (nt = w mod 4) -> no LDS staging needed.
// ---------------------------------------------------------------------------
__global__ __launch_bounds__(256, 1) void gru_chunk(
    const _Float16* __restrict__ gxn, const u16* __restrict__ Wimg,
    const u16* __restrict__ bhh_g, u16* __restrict__ h_all,
    float* __restrict__ hstate, int ck, int BC) {
    __shared__ __align__(16) u16 Hhi[2 * 10 * 64 * 8];  // 20 KB [mt][kt][lane][8]
    __shared__ __align__(16) u16 Hlo[2 * 10 * 64 * 8];  // 20 KB

    const int tid = threadIdx.x;
    const int lane = tid & 63, wv = tid >> 6, q = lane >> 4, c = lane & 15;
    const int b0 = blockIdx.x * 32;

    float bhh[5][3];
#pragma unroll
    for (int Ti = 0; Ti < 5; Ti++) {
        int u = (wv + 4 * Ti) * 16 + c;
#pragma unroll
        for (int g = 0; g < 3; g++)
            bhh[Ti][g] = (u < 300) ? bf2f(bhh_g[g * 300 + u]) : 0.f;
    }

    // Load carried h state (fp32) and build hi/lo fragment images.
    float hm[2][5][4];
#pragma unroll
    for (int mt = 0; mt < 2; mt++)
#pragma unroll
        for (int Ti = 0; Ti < 5; Ti++) {
            int T = wv + 4 * Ti;
            int u = T * 16 + c;
            int kt = T >> 1;
            int qp = ((T & 1) << 1) | (c >> 3);
            int j = c & 7;
#pragma unroll
            for (int reg = 0; reg < 4; reg++) {
                int m = mt * 16 + q * 4 + reg;
                float h = hstate[(size_t)(b0 + m) * 320 + u];
                hm[mt][Ti][reg] = h;
                int idx = ((mt * 10 + kt) * 64 + ((q * 4 + reg) | (qp << 4))) * 8 + j;
                u16 hi = f2bf(h);
                Hhi[idx] = hi;
                Hlo[idx] = f2bf(h - bf2f(hi));
            }
        }
    __syncthreads();

    for (int tt = 0; tt < 15; tt++) {
        // ---- issue ALL gate-input loads up front (land during W phase) ----
        f16x4 gxv[2][5][4];
        const _Float16* gxt = gxn + (size_t)tt * BC * 1280;
#pragma unroll
        for (int mt = 0; mt < 2; mt++)
#pragma unroll
            for (int Ti = 0; Ti < 5; Ti++) {
                int u = (wv + 4 * Ti) * 16 + c;
#pragma unroll
                for (int reg = 0; reg < 4; reg++) {
                    int m = mt * 16 + q * 4 + reg;
                    gxv[mt][Ti][reg] = *(const f16x4*)&gxt[((size_t)(b0 + m) * 320 + u) * 4];
                }
            }

        f32x4 acc[2][5][3];
#pragma unroll
        for (int mt = 0; mt < 2; mt++)
#pragma unroll
            for (int Ti = 0; Ti < 5; Ti++)
#pragma unroll
                for (int g = 0; g < 3; g++) {
                    f32x4 z = {0.f, 0.f, 0.f, 0.f};
                    acc[mt][Ti][g] = z;
                }

        auto loadW = [&](int kt, bf16x8* dst) {
#pragma unroll
            for (int Ti = 0; Ti < 5; Ti++)
#pragma unroll
                for (int g = 0; g < 3; g++) {
                    int nt = g * 20 + wv + 4 * Ti;
                    u16x8 tb = *(const u16x8*)&Wimg[((size_t)(nt * 10 + kt)) * 512 + lane * 8];
                    dst[Ti * 3 + g] = __builtin_bit_cast(bf16x8, tb);
                }
        };
        auto consume = [&](int kt, const bf16x8* bfr) {
            bf16x8 ahi[2], alo[2];
#pragma unroll
            for (int mt = 0; mt < 2; mt++) {
                u16x8 th = *(const u16x8*)&Hhi[((mt * 10 + kt) * 64 + lane) * 8];
                u16x8 tl = *(const u16x8*)&Hlo[((mt * 10 + kt) * 64 + lane) * 8];
                ahi[mt] = __builtin_bit_cast(bf16x8, th);
                alo[mt] = __builtin_bit_cast(bf16x8, tl);
            }
#pragma unroll
            for (int Ti = 0; Ti < 5; Ti++)
#pragma unroll
                for (int g = 0; g < 3; g++)
#pragma unroll
                    for (int mt = 0; mt < 2; mt++) {
                        acc[mt][Ti][g] = __builtin_amdgcn_mfma_f32_16x16x32_bf16(
                            ahi[mt], bfr[Ti * 3 + g], acc[mt][Ti][g], 0, 0, 0);
                        acc[mt][Ti][g] = __builtin_amdgcn_mfma_f32_16x16x32_bf16(
                            alo[mt], bfr[Ti * 3 + g], acc[mt][Ti][g], 0, 0, 0);
                    }
        };

        // Ping-pong over kt pairs: next kt's loads in flight during MFMAs.
        bf16x8 bfA[15], bfB[15];
        loadW(0, bfA);
#pragma unroll
        for (int kp = 0; kp < 5; kp++) {
            loadW(kp * 2 + 1, bfB);
            consume(kp * 2, bfA);
            if (kp < 4) loadW(kp * 2 + 2, bfA);
            consume(kp * 2 + 1, bfB);
        }

        // Gates (gxv already resident; C layout col=lane&15 -> u, row=q*4+reg -> m)
        const int tglob = ck * 15 + tt;
#pragma unroll
        for (int mt = 0; mt < 2; mt++)
#pragma unroll
            for (int Ti = 0; Ti < 5; Ti++) {
                int u = (wv + 4 * Ti) * 16 + c;
#pragma unroll
                for (int reg = 0; reg < 4; reg++) {
                    int m = mt * 16 + q * 4 + reg;
                    float xr = (float)gxv[mt][Ti][reg][0];
                    float xz = (float)gxv[mt][Ti][reg][1];
                    float xn = (float)gxv[mt][Ti][reg][2];
                    float hr = acc[mt][Ti][0][reg] + bhh[Ti][0];
                    float hz = acc[mt][Ti][1][reg] + bhh[Ti][1];
                    float hn = acc[mt][Ti][2][reg] + bhh[Ti][2];
                    float r = 1.f / (1.f + __expf(-(xr + hr)));
                    float z = 1.f / (1.f + __expf(-(xz + hz)));
                    float ex = __expf(2.f * (xn + r * hn));
                    float n = 1.f - 2.f / (ex + 1.f);  // tanh
                    float h = (1.f - z) * n + z * hm[mt][Ti][reg];
                    hm[mt][Ti][reg] = h;
                    h_all[((size_t)tglob * BC + (b0 + m)) * 320 + u] = f2bf(h);
                }
            }
        __syncthreads();  // fragment reads of h(t-1) done

        // Write new h into fragment images (hi + lo)
#pragma unroll
        for (int mt = 0; mt < 2; mt++)
#pragma unroll
            for (int Ti = 0; Ti < 5; Ti++) {
                int T = wv + 4 * Ti;
                int kt = T >> 1;
                int qp = ((T & 1) << 1) | (c >> 3);
                int j = c & 7;
#pragma unroll
                for (int reg = 0; reg < 4; reg++) {
                    int idx = ((mt * 10 + kt) * 64 + ((q * 4 + reg) | (qp << 4))) * 8 + j;
                    float h = hm[mt][Ti][reg];
                    u16 hi = f2bf(h);
                    Hhi[idx] = hi;
                    Hlo[idx] = f2bf(h - bf2f(hi));
                }
            }
        __syncthreads();
    }

    // Persist fp32 h state for the next chunk.
#pragma unroll
    for (int mt = 0; mt < 2; mt++)
#pragma unroll
        for (int Ti = 0; Ti < 5; Ti++) {
            int u = (wv + 4 * Ti) * 16 + c;
#pragma unroll
            for (int reg = 0; reg < 4; reg++) {
                int m = mt * 16 + q * 4 + reg;
                hstate[(size_t)(b0 + m) * 320 + u] = hm[mt][Ti][reg];
            }
        }
}

// ---------------------------------------------------------------------------
// Co-attention + pool + logits. One WG per batch row of the phase.
// ---------------------------------------------------------------------------
__global__ __launch_bounds__(256, 2) void coattn_kernel(
    const u16* __restrict__ h_all, const u16* __restrict__ smalls,
    void* __restrict__ outv, const int* __restrict__ flag, int phase, int BC) {
    __shared__ __align__(16) u16 himg[5 * 10 * 64 * 8];
    __shared__ float smacc[80], aArr[80], bArr[80], diagArr[80], attn[80], smv[80];
    __shared__ float pooled[320];
    __shared__ float scal[2];

    const u16* wCo = smalls + 2048;
    const u16* Wmy = smalls + 3072;
    const u16* lw = smalls + 3200;
    const u16* lb = smalls + 4704;
    const int f32out = flag[0];

    const int b = blockIdx.x;
    const int tid = threadIdx.x;
    const int lane = tid & 63, wv = tid >> 6, q = lane >> 4, c = lane & 15;

    for (int o = tid; o < 3200; o += 256) {
        int i = o / 40;
        int oc = o - i * 40;
        int kt = oc >> 2, qq = oc & 3;
        int e0 = kt * 32 + qq * 8;
        u16x8 v = {0, 0, 0, 0, 0, 0, 0, 0};
        if (i < 75) v = *(const u16x8*)(h_all + ((size_t)i * BC + b) * 320 + e0);
        *(u16x8*)&himg[(((i >> 4) * 10 + kt) * 64 + ((i & 15) | (qq << 4))) * 8] = v;
    }
    if (tid < 80) {
        smacc[tid] = 0.f; aArr[tid] = 0.f; bArr[tid] = 0.f;
        diagArr[tid] = 0.f; attn[tid] = 0.f;
    }
    __syncthreads();

    for (int pass = 0; pass < 2; pass++) {
        if (pass == 1 && wv != 0) break;
        int nt = (pass == 0) ? wv : 4;
        int jj = nt * 16 + c;
        bf16x8 bfr[10];
#pragma unroll
        for (int kt = 0; kt < 10; kt++) {
            int e0 = kt * 32 + q * 8;
            u16x8 res = {0, 0, 0, 0, 0, 0, 0, 0};
            if (jj < 75) {
                u16x8 hv = *(const u16x8*)&himg[((nt * 10 + kt) * 64 + lane) * 8];
                u16x8 wcv = load_row8(wCo + 600, e0);
#pragma unroll
                for (int j = 0; j < 8; j++) res[j] = f2bf(bf2f(hv[j]) * bf2f(wcv[j]));
            } else if (jj == 75) {
                res = load_row8(wCo, e0);  // wa
            } else if (jj == 76) {
                res = load_row8(wCo + 300, e0);  // wb
            }
            bfr[kt] = __builtin_bit_cast(bf16x8, res);
        }
        float wmyj = (jj < 75) ? bf2f(Wmy[jj]) : 0.f;

        for (int mt = 0; mt < 5; mt++) {
            f32x4 acc = {0.f, 0.f, 0.f, 0.f};
#pragma unroll
            for (int kt = 0; kt < 10; kt++) {
                u16x8 ta = *(const u16x8*)&himg[((mt * 10 + kt) * 64 + lane) * 8];
                bf16x8 a = __builtin_bit_cast(bf16x8, ta);
                acc = __builtin_amdgcn_mfma_f32_16x16x32_bf16(a, bfr[kt], acc, 0, 0, 0);
            }
#pragma unroll
            for (int reg = 0; reg < 4; reg++) {
                int i = mt * 16 + q * 4 + reg;
                float v = acc[reg];
                float p = v * wmyj;
                p += __shfl_xor(p, 1);
                p += __shfl_xor(p, 2);
                p += __shfl_xor(p, 4);
                p += __shfl_xor(p, 8);
                if (c == 0 && i < 75) atomicAdd(&smacc[i], p);
                if (jj == i && i < 75) diagArr[i] = v;
                if (jj == 75) aArr[i] = v;
                if (jj == 76) bArr[i] = v;
            }
        }
    }
    __syncthreads();

    if (tid < 64) {
        float w1 = bf2f(Wmy[tid]);
        float w2 = (tid + 64 < 75) ? bf2f(Wmy[tid + 64]) : 0.f;
        float s1 = w1 + w2;
        float s2 = w1 * bArr[tid] + ((tid + 64 < 75) ? w2 * bArr[tid + 64] : 0.f);
#pragma unroll
        for (int m = 1; m < 64; m <<= 1) {
            s1 += __shfl_xor(s1, m);
            s2 += __shfl_xor(s2, m);
        }
        if (tid == 0) { scal[0] = s1; scal[1] = s2; }
    }
    __syncthreads();

    float cb = bf2f(smalls[4712]);
    float wmyb = bf2f(smalls[4713]);
    if (tid < 75) {
        float Wi = bf2f(Wmy[tid]);
        smv[tid] = smacc[tid] - diagArr[tid] * Wi + (aArr[tid] + cb) * (scal[0] - Wi) +
                   scal[1] - bArr[tid] * Wi + wmyb;
    }
    __syncthreads();

    if (tid < 64) {
        float v1 = smv[tid];
        float v2 = (tid + 64 < 75) ? smv[tid + 64] : -1e30f;
        float mx = fmaxf(v1, v2);
#pragma unroll
        for (int m = 1; m < 64; m <<= 1) mx = fmaxf(mx, __shfl_xor(mx, m));
        float e1 = __expf(v1 - mx);
        float e2 = (tid + 64 < 75) ? __expf(v2 - mx) : 0.f;
        float s = e1 + e2;
#pragma unroll
        for (int m = 1; m < 64; m <<= 1) s += __shfl_xor(s, m);
        attn[tid] = e1 / s;
        if (tid + 64 < 75) attn[tid + 64] = e2 / s;
    }
    __syncthreads();

    for (int d = tid; d < 320; d += 256) {
        float accp = 0.f;
        for (int i = 0; i < 75; i++)
            accp += attn[i] * bf2f(h_all[((size_t)i * BC + b) * 320 + d]);
        pooled[d] = accp;
    }
    __syncthreads();

    if (tid < 160) {
        int o = tid >> 5, d0 = tid & 31;
        float accl = 0.f;
        for (int d = d0; d < 320; d += 32)
            accl += (d < 300) ? pooled[d] * bf2f(lw[o * 300 + d]) : 0.f;
#pragma unroll
        for (int m = 1; m < 32; m <<= 1) accl += __shfl_xor(accl, m);
        if (d0 == 0) {
            float v = accl + bf2f(lb[o]);
            size_t idx = (size_t)(phase * BC + b) * 5 + o;
            if (f32out) ((float*)outv)[idx] = v;
            else ((u16*)outv)[idx] = f2bf(v);
        }
    }
}

// ---------------------------------------------------------------------------
extern "C" void kernel_launch(void* const* d_in, const int* in_sizes, int n_in,
                              void* d_out, int out_size, void* d_ws, size_t ws_size,
                              hipStream_t stream) {
    const int* seq = (const int*)d_in[0];

    char* p = (char*)d_ws;
    int* flag = (int*)p;                        // @0
    u16* smalls = (u16*)(p + 16);               // 4720 u16
    u16* WihImg = (u16*)(p + 9488);
    u16* WhhImg = (u16*)(p + 623888);
    u16* Wih_c = (u16*)(p + 1238288);
    u16* Whh_c = (u16*)(p + 1778288);
    const unsigned long long fixed_end = 2318288ull;

    // per-BC: gxn 15*BC*2560 + h_all 75*BC*640 + hstate BC*1280 = BC*87680
    auto req = [&](long long BC) -> unsigned long long {
        return fixed_end + (unsigned long long)BC * 87680ull + 1048576ull;
    };
    int BC = 256, bshift = 8;
    if (ws_size >= req(2048)) { BC = 2048; bshift = 11; }
    else if (ws_size >= req(1024)) { BC = 1024; bshift = 10; }
    else if (ws_size >= req(512)) { BC = 512; bshift = 9; }
    const int P = 2048 / BC;

    unsigned long long gx_b = 15ull * BC * 2560ull;
    unsigned long long h_b = 75ull * BC * 640ull;
    _Float16* gxn = (_Float16*)(p + fixed_end);
    u16* h_all = (u16*)(p + fixed_end + gx_b);
    float* hstate = (float*)(p + fixed_end + gx_b + h_b);

    // 1. dtype detection + canonicalization (weights only; emb read raw)
    detect_dtype<<<dim3(1), dim3(256), 0, stream>>>((const u16*)d_in[1], flag);
    conv_big<<<dim3((270000 + 2047) / 2048), dim3(256), 0, stream>>>(
        d_in[2], Wih_c, 270000, flag);
    conv_big<<<dim3((270000 + 2047) / 2048), dim3(256), 0, stream>>>(
        d_in[3], Whh_c, 270000, flag);
    conv_smalls<<<dim3(17), dim3(256), 0, stream>>>(
        d_in[4], d_in[5], d_in[6], d_in[7], d_in[8], d_in[9], d_in[10], d_in[11],
        smalls, flag);

    // 2. weight fragment images
    prep_img<<<dim3(150), dim3(256), 0, stream>>>(Wih_c, WihImg);
    prep_img<<<dim3(150), dim3(256), 0, stream>>>(Whh_c, WhhImg);

    // 3. phases
    for (int phase = 0; phase < P; phase++) {
        zero_hstate<<<dim3(BC * 320 / 1024), dim3(256), 0, stream>>>(hstate);
        for (int ck = 0; ck < 5; ck++) {
            gemm1_kernel<<<dim3(15 * BC / 192, 5), dim3(256), 0, stream>>>(
                seq, d_in[1], WihImg, smalls /*bih*/, gxn, ck, phase, BC, bshift, flag);
            gru_chunk<<<dim3(BC / 32), dim3(256), 0, stream>>>(
                gxn, WhhImg, smalls + 1024 /*bhh*/, h_all, hstate, ck, BC);
        }
        coattn_kernel<<<dim3(BC), dim3(256), 0, stream>>>(h_all, smalls, d_out, flag,
                                                          phase, BC);
    }
}

// Round 8
// 2167.178 us; speedup vs baseline: 1.7776x; 1.4036x over previous
//
#include <hip/hip_runtime.h>
#include <stdint.h>

// CoAttention: emb-gather + GRU(75 steps) + co-attention pool + logits.
// Inputs fp32 in memory (runtime-detected; weights canonicalized to bf16).
//
// ws layout:
//   flag    int           @ 0          (16 B)
//   smalls  bf16[4720]    @ 16         (9472 B)
//   WihImg  bf16          @ 9488       (614400 B)
//   WhhImg  bf16          @ 623888     (614400 B)
//   Wih_c   bf16[270000]  @ 1238288    (540000 B)
//   Whh_c   bf16[270000]  @ 1778288    (540000 B)
//   gxn     fp16          @ 2318288    (15*BC*2560 B)  gate-packed (r,z,n,pad)
//   h_all   bf16          @ +gxn       (75*BC*640 B)
//   hstate  fp32          @ +h         (BC*1280 B)
// BC=2048 total ~182.9 MB (proven budget)

typedef float f32x4 __attribute__((ext_vector_type(4)));
typedef short bf16x8 __attribute__((ext_vector_type(8)));
typedef _Float16 f16x4 __attribute__((ext_vector_type(4)));
typedef unsigned short u16;
typedef u16 u16x8 __attribute__((ext_vector_type(8)));
typedef u16 u16x4 __attribute__((ext_vector_type(4)));

#define DI __device__ __forceinline__

DI float bf2f(u16 v) {
    uint32_t u = ((uint32_t)v) << 16;
    float f;
    __builtin_memcpy(&f, &u, 4);
    return f;
}
DI u16 f2bf(float f) {  // round-to-nearest-even
    uint32_t u;
    __builtin_memcpy(&u, &f, 4);
    uint32_t r = u + 0x7fffu + ((u >> 16) & 1u);
    return (u16)(r >> 16);
}
DI u16 cvt1(const void* p, int i, int f32m) {
    return f32m ? f2bf(((const float*)p)[i]) : ((const u16*)p)[i];
}

DI u16x8 load_row8(const u16* __restrict__ base, int e0) {
    u16x4 z = {0, 0, 0, 0};
    u16x4 lo = (e0 < 300) ? *(const u16x4*)(base + e0) : z;
    u16x4 hi = (e0 + 4 < 300) ? *(const u16x4*)(base + e0 + 4) : z;
    u16x8 r;
    r[0] = lo[0]; r[1] = lo[1]; r[2] = lo[2]; r[3] = lo[3];
    r[4] = hi[0]; r[5] = hi[1]; r[6] = hi[2]; r[7] = hi[3];
    return r;
}
DI u16x8 load_row8_f32(const float* __restrict__ base, int e0) {
    f32x4 z = {0.f, 0.f, 0.f, 0.f};
    f32x4 lo = (e0 < 300) ? *(const f32x4*)(base + e0) : z;
    f32x4 hi = (e0 + 4 < 300) ? *(const f32x4*)(base + e0 + 4) : z;
    u16x8 r;
    r[0] = f2bf(lo[0]); r[1] = f2bf(lo[1]); r[2] = f2bf(lo[2]); r[3] = f2bf(lo[3]);
    r[4] = f2bf(hi[0]); r[5] = f2bf(hi[1]); r[6] = f2bf(hi[2]); r[7] = f2bf(hi[3]);
    return r;
}

// ---------------------------------------------------------------------------
__global__ __launch_bounds__(256) void detect_dtype(const u16* __restrict__ raw,
                                                    int* __restrict__ flag) {
    __shared__ int cnt;
    if (threadIdx.x == 0) cnt = 0;
    __syncthreads();
    int local = 0;
    for (int i = threadIdx.x; i < 4096; i += 256) {
        int e = (raw[i] >> 7) & 0xFF;
        if (e >= 140) local++;
    }
    atomicAdd(&cnt, local);
    __syncthreads();
    if (threadIdx.x == 0) flag[0] = (cnt > 256) ? 1 : 0;
}

__global__ __launch_bounds__(256) void conv_big(const void* __restrict__ in,
                                                u16* __restrict__ outp, int n,
                                                const int* __restrict__ flag) {
    const int f32m = flag[0];
    int i0 = (blockIdx.x * 256 + threadIdx.x) * 8;
#pragma unroll
    for (int k = 0; k < 8; k++) {
        int i = i0 + k;
        if (i < n) outp[i] = cvt1(in, i, f32m);
    }
}

__global__ __launch_bounds__(256) void conv_smalls(
    const void* bih_r, const void* bhh_r, const void* wCo_r, const void* wCob_r,
    const void* Wmy_r, const void* Wmyb_r, const void* lw_r, const void* lb_r,
    u16* __restrict__ smalls, const int* __restrict__ flag) {
    const int f32m = flag[0];
    int t = blockIdx.x * 256 + threadIdx.x;
    if (t < 900) smalls[t] = cvt1(bih_r, t, f32m);
    else if (t < 1800) smalls[1024 + t - 900] = cvt1(bhh_r, t - 900, f32m);
    else if (t < 2700) smalls[2048 + t - 1800] = cvt1(wCo_r, t - 1800, f32m);
    else if (t < 2775) smalls[3072 + t - 2700] = cvt1(Wmy_r, t - 2700, f32m);
    else if (t < 4275) smalls[3200 + t - 2775] = cvt1(lw_r, t - 2775, f32m);
    else if (t < 4280) smalls[4704 + t - 4275] = cvt1(lb_r, t - 4275, f32m);
    else if (t == 4280) smalls[4712] = cvt1(wCob_r, 0, f32m);
    else if (t == 4281) smalls[4713] = cvt1(Wmyb_r, 0, f32m);
}

// ---------------------------------------------------------------------------
// Pack a (900 x 300) canonical bf16 weight into MFMA B-fragment image:
// img[nt<60][kt<10][lane<64][8], g = nt*16 + (lane&15) in padded 960 space.
// ---------------------------------------------------------------------------
__global__ __launch_bounds__(256) void prep_img(const u16* __restrict__ W,
                                                u16* __restrict__ img) {
    int t = blockIdx.x * 256 + threadIdx.x;
    if (t >= 60 * 10 * 64) return;
    int lane = t & 63;
    int kt = (t >> 6) % 10;
    int nt = t / 640;
    int g = nt * 16 + (lane & 15);
    int gate = g / 320, u = g - gate * 320;
    int e0 = kt * 32 + (lane >> 4) * 8;
    u16x8 v;
    if (u < 300) {
        v = load_row8(W + (size_t)(gate * 300 + u) * 300, e0);
    } else {
        u16x8 z = {0, 0, 0, 0, 0, 0, 0, 0};
        v = z;
    }
    *(u16x8*)&img[(size_t)t * 8] = v;
}

__global__ __launch_bounds__(256) void zero_hstate(float* __restrict__ hs) {
    int t = blockIdx.x * 256 + threadIdx.x;
    f32x4 z = {0.f, 0.f, 0.f, 0.f};
    ((f32x4*)hs)[t] = z;
}

// ---------------------------------------------------------------------------
// GEMM1: gxn[(m*320+u)*4+gate] fp16, gate-packed per (m,u).
// Tile 192x192, K=320. Grid (15*BC/192, 5). emb read raw (fp32 or bf16).
// ---------------------------------------------------------------------------
__global__ __launch_bounds__(256, 2) void gemm1_kernel(
    const int* __restrict__ seq, const void* __restrict__ emb_raw,
    const u16* __restrict__ Wimg, const u16* __restrict__ bih,
    _Float16* __restrict__ gxn, int ck, int phase, int BC, int bshift,
    const int* __restrict__ flag) {
    __shared__ int ids[192];
    __shared__ __align__(16) u16 Aimg[12 * 64 * 8];
    __shared__ __align__(16) u16 Bbuf[12 * 64 * 8];

    const int tid = threadIdx.x;
    const int lane = tid & 63, wv = tid >> 6, q = lane >> 4, c = lane & 15;
    const int m0 = blockIdx.x * 192;
    const int nb = blockIdx.y;
    const int f32m = flag[0];

    if (tid < 192) {
        int m = m0 + tid;
        int bc = m & (BC - 1);
        int tp = m >> bshift;
        ids[tid] = seq[(size_t)(phase * BC + bc) * 75 + ck * 15 + tp];
    }
    __syncthreads();

    f32x4 acc[3][12];
#pragma unroll
    for (int mt = 0; mt < 3; mt++)
#pragma unroll
        for (int nt = 0; nt < 12; nt++) {
            f32x4 z = {0.f, 0.f, 0.f, 0.f};
            acc[mt][nt] = z;
        }

    for (int kt = 0; kt < 10; kt++) {
#pragma unroll
        for (int s = 0; s < 3; s++) {
            int o = tid + s * 256;
            int qq = o / 192;
            int r = o - qq * 192;
            int e0 = kt * 32 + qq * 8;
            u16x8 v = f32m ? load_row8_f32((const float*)emb_raw + (size_t)ids[r] * 300, e0)
                           : load_row8((const u16*)emb_raw + (size_t)ids[r] * 300, e0);
            *(u16x8*)&Aimg[(((r >> 4) * 64) + ((r & 15) | (qq << 4))) * 8] = v;
        }
#pragma unroll
        for (int s = 0; s < 3; s++) {
            int ch = tid + s * 256;
            *(u16x8*)&Bbuf[ch * 8] =
                *(const u16x8*)&Wimg[(((size_t)(nb * 12 + (ch >> 6)) * 10 + kt) * 64 + (ch & 63)) * 8];
        }
        __syncthreads();

        bf16x8 a[3];
#pragma unroll
        for (int mt = 0; mt < 3; mt++) {
            u16x8 tmp = *(const u16x8*)&Aimg[(((wv * 3 + mt) * 64) + lane) * 8];
            a[mt] = __builtin_bit_cast(bf16x8, tmp);
        }
#pragma unroll
        for (int nt = 0; nt < 12; nt++) {
            u16x8 tb = *(const u16x8*)&Bbuf[(nt * 64 + lane) * 8];
            bf16x8 b = __builtin_bit_cast(bf16x8, tb);
#pragma unroll
            for (int mt = 0; mt < 3; mt++)
                acc[mt][nt] = __builtin_amdgcn_mfma_f32_16x16x32_bf16(a[mt], b, acc[mt][nt], 0, 0, 0);
        }
        __syncthreads();
    }

#pragma unroll
    for (int nt = 0; nt < 12; nt++) {
        int g = nb * 192 + nt * 16 + c;
        int gate = g / 320, u = g - gate * 320;
        float bias = (u < 300) ? bf2f(bih[gate * 300 + u]) : 0.f;
#pragma unroll
        for (int mt = 0; mt < 3; mt++) {
            int mrow = m0 + (wv * 3 + mt) * 16 + q * 4;
#pragma unroll
            for (int reg = 0; reg < 4; reg++) {
                gxn[((size_t)(mrow + reg) * 320 + u) * 4 + gate] =
                    (_Float16)(acc[mt][nt][reg] + bias);
            }
        }
    }
}

// ---------------------------------------------------------------------------
// GRU chunk: BC/32 WGs x 256 threads (R4's proven no-spill config).
// Latency fixes vs R4, within the 256-VGPR regular-file budget:
//  - all 40 gate-input dwordx2 loads issued at step start (hidden under W
//    phase; gxn is gate-packed so 120 scalar loads became 40 vector loads)
//  - W fragments single-buffered (ping-pong spilled in R7: 256-VGPR cap)
// accs (120 regs) live in AGPRs; regular-VGPR demand ~240 -> no spill.
// ---------------------------------------------------------------------------
__global__ __launch_bounds__(256, 1) void gru_chunk(
    const _Float16* __restrict__ gxn, const u16* __restrict__ Wimg,
    const u16* __restrict__ bhh_g, u16* __restrict__ h_all,
    float* __restrict__ hstate, int ck, int BC) {
    __shared__ __align__(16) u16 Hhi[2 * 10 * 64 * 8];  // 20 KB [mt][kt][lane][8]
    __shared__ __align__(16) u16 Hlo[2 * 10 * 64 * 8];  // 20 KB

    const int tid = threadIdx.x;
    const int lane = tid & 63, wv = tid >> 6, q = lane >> 4, c = lane & 15;
    const int b0 = blockIdx.x * 32;

    float bhh[5][3];
#pragma unroll
    for (int Ti = 0; Ti < 5; Ti++) {
        int u = (wv + 4 * Ti) * 16 + c;
#pragma unroll
        for (int g = 0; g < 3; g++)
            bhh[Ti][g] = (u < 300) ? bf2f(bhh_g[g * 300 + u]) : 0.f;
    }

    float hm[2][5][4];
#pragma unroll
    for (int mt = 0; mt < 2; mt++)
#pragma unroll
        for (int Ti = 0; Ti < 5; Ti++) {
            int T = wv + 4 * Ti;
            int u = T * 16 + c;
            int kt = T >> 1;
            int qp = ((T & 1) << 1) | (c >> 3);
            int j = c & 7;
#pragma unroll
            for (int reg = 0; reg < 4; reg++) {
                int m = mt * 16 + q * 4 + reg;
                float h = hstate[(size_t)(b0 + m) * 320 + u];
                hm[mt][Ti][reg] = h;
                int idx = ((mt * 10 + kt) * 64 + ((q * 4 + reg) | (qp << 4))) * 8 + j;
                u16 hi = f2bf(h);
                Hhi[idx] = hi;
                Hlo[idx] = f2bf(h - bf2f(hi));
            }
        }
    __syncthreads();

    for (int tt = 0; tt < 15; tt++) {
        // ---- issue ALL gate-input loads up front (land during W phase) ----
        f16x4 gxv[2][5][4];
        const _Float16* gxt = gxn + (size_t)tt * BC * 1280;
#pragma unroll
        for (int mt = 0; mt < 2; mt++)
#pragma unroll
            for (int Ti = 0; Ti < 5; Ti++) {
                int u = (wv + 4 * Ti) * 16 + c;
#pragma unroll
                for (int reg = 0; reg < 4; reg++) {
                    int m = mt * 16 + q * 4 + reg;
                    gxv[mt][Ti][reg] = *(const f16x4*)&gxt[((size_t)(b0 + m) * 320 + u) * 4];
                }
            }

        f32x4 acc[2][5][3];
#pragma unroll
        for (int mt = 0; mt < 2; mt++)
#pragma unroll
            for (int Ti = 0; Ti < 5; Ti++)
#pragma unroll
                for (int g = 0; g < 3; g++) {
                    f32x4 z = {0.f, 0.f, 0.f, 0.f};
                    acc[mt][Ti][g] = z;
                }

        // gh = (h_hi + h_lo) @ W_hh^T  (K = 320, 10 k-tiles, single-buffered)
        for (int kt = 0; kt < 10; kt++) {
            bf16x8 ahi[2], alo[2];
#pragma unroll
            for (int mt = 0; mt < 2; mt++) {
                u16x8 th = *(const u16x8*)&Hhi[((mt * 10 + kt) * 64 + lane) * 8];
                u16x8 tl = *(const u16x8*)&Hlo[((mt * 10 + kt) * 64 + lane) * 8];
                ahi[mt] = __builtin_bit_cast(bf16x8, th);
                alo[mt] = __builtin_bit_cast(bf16x8, tl);
            }
            bf16x8 bf[15];
#pragma unroll
            for (int Ti = 0; Ti < 5; Ti++)
#pragma unroll
                for (int g = 0; g < 3; g++) {
                    int nt = g * 20 + wv + 4 * Ti;
                    u16x8 tb = *(const u16x8*)&Wimg[((size_t)(nt * 10 + kt)) * 512 + lane * 8];
                    bf[Ti * 3 + g] = __builtin_bit_cast(bf16x8, tb);
                }
#pragma unroll
            for (int Ti = 0; Ti < 5; Ti++)
#pragma unroll
                for (int g = 0; g < 3; g++)
#pragma unroll
                    for (int mt = 0; mt < 2; mt++) {
                        acc[mt][Ti][g] = __builtin_amdgcn_mfma_f32_16x16x32_bf16(
                            ahi[mt], bf[Ti * 3 + g], acc[mt][Ti][g], 0, 0, 0);
                        acc[mt][Ti][g] = __builtin_amdgcn_mfma_f32_16x16x32_bf16(
                            alo[mt], bf[Ti * 3 + g], acc[mt][Ti][g], 0, 0, 0);
                    }
        }

        // Gates (gxv resident; C layout col=lane&15 -> u, row=q*4+reg -> m)
        const int tglob = ck * 15 + tt;
#pragma unroll
        for (int mt = 0; mt < 2; mt++)
#pragma unroll
            for (int Ti = 0; Ti < 5; Ti++) {
                int u = (wv + 4 * Ti) * 16 + c;
#pragma unroll
                for (int reg = 0; reg < 4; reg++) {
                    int m = mt * 16 + q * 4 + reg;
                    float xr = (float)gxv[mt][Ti][reg][0];
                    float xz = (float)gxv[mt][Ti][reg][1];
                    float xn = (float)gxv[mt][Ti][reg][2];
                    float hr = acc[mt][Ti][0][reg] + bhh[Ti][0];
                    float hz = acc[mt][Ti][1][reg] + bhh[Ti][1];
                    float hn = acc[mt][Ti][2][reg] + bhh[Ti][2];
                    float r = 1.f / (1.f + __expf(-(xr + hr)));
                    float z = 1.f / (1.f + __expf(-(xz + hz)));
                    float ex = __expf(2.f * (xn + r * hn));
                    float n = 1.f - 2.f / (ex + 1.f);  // tanh
                    float h = (1.f - z) * n + z * hm[mt][Ti][reg];
                    hm[mt][Ti][reg] = h;
                    h_all[((size_t)tglob * BC + (b0 + m)) * 320 + u] = f2bf(h);
                }
            }
        __syncthreads();  // fragment reads of h(t-1) done

        // Write new h into fragment images (hi + lo)
#pragma unroll
        for (int mt = 0; mt < 2; mt++)
#pragma unroll
            for (int Ti = 0; Ti < 5; Ti++) {
                int T = wv + 4 * Ti;
                int kt = T >> 1;
                int qp = ((T & 1) << 1) | (c >> 3);
                int j = c & 7;
#pragma unroll
                for (int reg = 0; reg < 4; reg++) {
                    int idx = ((mt * 10 + kt) * 64 + ((q * 4 + reg) | (qp << 4))) * 8 + j;
                    float h = hm[mt][Ti][reg];
                    u16 hi = f2bf(h);
                    Hhi[idx] = hi;
                    Hlo[idx] = f2bf(h - bf2f(hi));
                }
            }
        __syncthreads();
    }

    // Persist fp32 h state for the next chunk.
#pragma unroll
    for (int mt = 0; mt < 2; mt++)
#pragma unroll
        for (int Ti = 0; Ti < 5; Ti++) {
            int u = (wv + 4 * Ti) * 16 + c;
#pragma unroll
            for (int reg = 0; reg < 4; reg++) {
                int m = mt * 16 + q * 4 + reg;
                hstate[(size_t)(b0 + m) * 320 + u] = hm[mt][Ti][reg];
            }
        }
}

// ---------------------------------------------------------------------------
// Co-attention + pool + logits. One WG per batch row of the phase.
// ---------------------------------------------------------------------------
__global__ __launch_bounds__(256, 2) void coattn_kernel(
    const u16* __restrict__ h_all, const u16* __restrict__ smalls,
    void* __restrict__ outv, const int* __restrict__ flag, int phase, int BC) {
    __shared__ __align__(16) u16 himg[5 * 10 * 64 * 8];
    __shared__ float smacc[80], aArr[80], bArr[80], diagArr[80], attn[80], smv[80];
    __shared__ float pooled[320];
    __shared__ float scal[2];

    const u16* wCo = smalls + 2048;
    const u16* Wmy = smalls + 3072;
    const u16* lw = smalls + 3200;
    const u16* lb = smalls + 4704;
    const int f32out = flag[0];

    const int b = blockIdx.x;
    const int tid = threadIdx.x;
    const int lane = tid & 63, wv = tid >> 6, q = lane >> 4, c = lane & 15;

    for (int o = tid; o < 3200; o += 256) {
        int i = o / 40;
        int oc = o - i * 40;
        int kt = oc >> 2, qq = oc & 3;
        int e0 = kt * 32 + qq * 8;
        u16x8 v = {0, 0, 0, 0, 0, 0, 0, 0};
        if (i < 75) v = *(const u16x8*)(h_all + ((size_t)i * BC + b) * 320 + e0);
        *(u16x8*)&himg[(((i >> 4) * 10 + kt) * 64 + ((i & 15) | (qq << 4))) * 8] = v;
    }
    if (tid < 80) {
        smacc[tid] = 0.f; aArr[tid] = 0.f; bArr[tid] = 0.f;
        diagArr[tid] = 0.f; attn[tid] = 0.f;
    }
    __syncthreads();

    for (int pass = 0; pass < 2; pass++) {
        if (pass == 1 && wv != 0) break;
        int nt = (pass == 0) ? wv : 4;
        int jj = nt * 16 + c;
        bf16x8 bfr[10];
#pragma unroll
        for (int kt = 0; kt < 10; kt++) {
            int e0 = kt * 32 + q * 8;
            u16x8 res = {0, 0, 0, 0, 0, 0, 0, 0};
            if (jj < 75) {
                u16x8 hv = *(const u16x8*)&himg[((nt * 10 + kt) * 64 + lane) * 8];
                u16x8 wcv = load_row8(wCo + 600, e0);
#pragma unroll
                for (int j = 0; j < 8; j++) res[j] = f2bf(bf2f(hv[j]) * bf2f(wcv[j]));
            } else if (jj == 75) {
                res = load_row8(wCo, e0);  // wa
            } else if (jj == 76) {
                res = load_row8(wCo + 300, e0);  // wb
            }
            bfr[kt] = __builtin_bit_cast(bf16x8, res);
        }
        float wmyj = (jj < 75) ? bf2f(Wmy[jj]) : 0.f;

        for (int mt = 0; mt < 5; mt++) {
            f32x4 acc = {0.f, 0.f, 0.f, 0.f};
#pragma unroll
            for (int kt = 0; kt < 10; kt++) {
                u16x8 ta = *(const u16x8*)&himg[((mt * 10 + kt) * 64 + lane) * 8];
                bf16x8 a = __builtin_bit_cast(bf16x8, ta);
                acc = __builtin_amdgcn_mfma_f32_16x16x32_bf16(a, bfr[kt], acc, 0, 0, 0);
            }
#pragma unroll
            for (int reg = 0; reg < 4; reg++) {
                int i = mt * 16 + q * 4 + reg;
                float v = acc[reg];
                float p = v * wmyj;
                p += __shfl_xor(p, 1);
                p += __shfl_xor(p, 2);
                p += __shfl_xor(p, 4);
                p += __shfl_xor(p, 8);
                if (c == 0 && i < 75) atomicAdd(&smacc[i], p);
                if (jj == i && i < 75) diagArr[i] = v;
                if (jj == 75) aArr[i] = v;
                if (jj == 76) bArr[i] = v;
            }
        }
    }
    __syncthreads();

    if (tid < 64) {
        float w1 = bf2f(Wmy[tid]);
        float w2 = (tid + 64 < 75) ? bf2f(Wmy[tid + 64]) : 0.f;
        float s1 = w1 + w2;
        float s2 = w1 * bArr[tid] + ((tid + 64 < 75) ? w2 * bArr[tid + 64] : 0.f);
#pragma unroll
        for (int m = 1; m < 64; m <<= 1) {
            s1 += __shfl_xor(s1, m);
            s2 += __shfl_xor(s2, m);
        }
        if (tid == 0) { scal[0] = s1; scal[1] = s2; }
    }
    __syncthreads();

    float cb = bf2f(smalls[4712]);
    float wmyb = bf2f(smalls[4713]);
    if (tid < 75) {
        float Wi = bf2f(Wmy[tid]);
        smv[tid] = smacc[tid] - diagArr[tid] * Wi + (aArr[tid] + cb) * (scal[0] - Wi) +
                   scal[1] - bArr[tid] * Wi + wmyb;
    }
    __syncthreads();

    if (tid < 64) {
        float v1 = smv[tid];
        float v2 = (tid + 64 < 75) ? smv[tid + 64] : -1e30f;
        float mx = fmaxf(v1, v2);
#pragma unroll
        for (int m = 1; m < 64; m <<= 1) mx = fmaxf(mx, __shfl_xor(mx, m));
        float e1 = __expf(v1 - mx);
        float e2 = (tid + 64 < 75) ? __expf(v2 - mx) : 0.f;
        float s = e1 + e2;
#pragma unroll
        for (int m = 1; m < 64; m <<= 1) s += __shfl_xor(s, m);
        attn[tid] = e1 / s;
        if (tid + 64 < 75) attn[tid + 64] = e2 / s;
    }
    __syncthreads();

    for (int d = tid; d < 320; d += 256) {
        float accp = 0.f;
        for (int i = 0; i < 75; i++)
            accp += attn[i] * bf2f(h_all[((size_t)i * BC + b) * 320 + d]);
        pooled[d] = accp;
    }
    __syncthreads();

    if (tid < 160) {
        int o = tid >> 5, d0 = tid & 31;
        float accl = 0.f;
        for (int d = d0; d < 320; d += 32)
            accl += (d < 300) ? pooled[d] * bf2f(lw[o * 300 + d]) : 0.f;
#pragma unroll
        for (int m = 1; m < 32; m <<= 1) accl += __shfl_xor(accl, m);
        if (d0 == 0) {
            float v = accl + bf2f(lb[o]);
            size_t idx = (size_t)(phase * BC + b) * 5 + o;
            if (f32out) ((float*)outv)[idx] = v;
            else ((u16*)outv)[idx] = f2bf(v);
        }
    }
}

// ---------------------------------------------------------------------------
extern "C" void kernel_launch(void* const* d_in, const int* in_sizes, int n_in,
                              void* d_out, int out_size, void* d_ws, size_t ws_size,
                              hipStream_t stream) {
    const int* seq = (const int*)d_in[0];

    char* p = (char*)d_ws;
    int* flag = (int*)p;                        // @0
    u16* smalls = (u16*)(p + 16);               // 4720 u16
    u16* WihImg = (u16*)(p + 9488);
    u16* WhhImg = (u16*)(p + 623888);
    u16* Wih_c = (u16*)(p + 1238288);
    u16* Whh_c = (u16*)(p + 1778288);
    const unsigned long long fixed_end = 2318288ull;

    auto req = [&](long long BC) -> unsigned long long {
        return fixed_end + (unsigned long long)BC * 87680ull + 1048576ull;
    };
    int BC = 256, bshift = 8;
    if (ws_size >= req(2048)) { BC = 2048; bshift = 11; }
    else if (ws_size >= req(1024)) { BC = 1024; bshift = 10; }
    else if (ws_size >= req(512)) { BC = 512; bshift = 9; }
    const int P = 2048 / BC;

    unsigned long long gx_b = 15ull * BC * 2560ull;
    unsigned long long h_b = 75ull * BC * 640ull;
    _Float16* gxn = (_Float16*)(p + fixed_end);
    u16* h_all = (u16*)(p + fixed_end + gx_b);
    float* hstate = (float*)(p + fixed_end + gx_b + h_b);

    detect_dtype<<<dim3(1), dim3(256), 0, stream>>>((const u16*)d_in[1], flag);
    conv_big<<<dim3((270000 + 2047) / 2048), dim3(256), 0, stream>>>(
        d_in[2], Wih_c, 270000, flag);
    conv_big<<<dim3((270000 + 2047) / 2048), dim3(256), 0, stream>>>(
        d_in[3], Whh_c, 270000, flag);
    conv_smalls<<<dim3(17), dim3(256), 0, stream>>>(
        d_in[4], d_in[5], d_in[6], d_in[7], d_in[8], d_in[9], d_in[10], d_in[11],
        smalls, flag);

    prep_img<<<dim3(150), dim3(256), 0, stream>>>(Wih_c, WihImg);
    prep_img<<<dim3(150), dim3(256), 0, stream>>>(Whh_c, WhhImg);

    for (int phase = 0; phase < P; phase++) {
        zero_hstate<<<dim3(BC * 320 / 1024), dim3(256), 0, stream>>>(hstate);
        for (int ck = 0; ck < 5; ck++) {
            gemm1_kernel<<<dim3(15 * BC / 192, 5), dim3(256), 0, stream>>>(
                seq, d_in[1], WihImg, smalls /*bih*/, gxn, ck, phase, BC, bshift, flag);
            gru_chunk<<<dim3(BC / 32), dim3(256), 0, stream>>>(
                gxn, WhhImg, smalls + 1024 /*bhh*/, h_all, hstate, ck, BC);
        }
        coattn_kernel<<<dim3(BC), dim3(256), 0, stream>>>(h_all, smalls, d_out, flag,
                                                          phase, BC);
    }
}